// Round 11
// baseline (604.744 us; speedup 1.0000x reference)
//
#include <hip/hip_runtime.h>
#include <hip/hip_fp16.h>

#define N_NODES 50000
#define N_EDGES 800000
#define NGRAPH  256
#define FDIM    64
#define EDIM    16
#define NT      (N_NODES / 16)      // 3125 node tiles (exact)
#define SH      8                   // CSR counter shards
#define M8      (N_NODES * SH)
#define NB8     ((M8 + 255) / 256)
#define CH8     ((NB8 + 255) / 256)

using half8  = __attribute__((ext_vector_type(8))) _Float16;
using float4v = __attribute__((ext_vector_type(4))) float;

__device__ __forceinline__ unsigned hadd2u(unsigned a, unsigned b) {
    __half2 r = __hadd2(__builtin_bit_cast(__half2, a), __builtin_bit_cast(__half2, b));
    return __builtin_bit_cast(unsigned, r);
}

// ---------------- small setup kernels ----------------

__global__ void k_count(const int* __restrict__ dst, int* __restrict__ cnt8) {
    int e = blockIdx.x * blockDim.x + threadIdx.x;
    if (e < N_EDGES) atomicAdd(&cnt8[dst[e] * SH + (e & (SH - 1))], 1);
}

__global__ void k_cvt_x(const float* __restrict__ x, __half* __restrict__ x16) {
    int t = blockIdx.x * blockDim.x + threadIdx.x;
    if (t < N_NODES * FDIM) x16[t] = __float2half(x[t]);
}

__global__ void k_blksum(const int* __restrict__ cnt8, int* __restrict__ blksum) {
    __shared__ int red[4];
    int b = blockIdx.x, t = threadIdx.x;
    int idx = b * 256 + t;
    int s = (idx < M8) ? cnt8[idx] : 0;
#pragma unroll
    for (int off = 32; off > 0; off >>= 1) s += __shfl_down(s, off, 64);
    int lane = t & 63, wid = t >> 6;
    if (lane == 0) red[wid] = s;
    __syncthreads();
    if (t == 0) blksum[b] = red[0] + red[1] + red[2] + red[3];
}

__global__ void k_scanblk(const int* __restrict__ blksum, int* __restrict__ boff,
                          int* __restrict__ rowp8) {
    __shared__ int sh[256];
    int t = threadIdx.x;
    int base = t * CH8;
    int v[CH8];
    int s = 0;
#pragma unroll
    for (int i = 0; i < CH8; i++) {
        int idx = base + i;
        v[i] = (idx < NB8) ? blksum[idx] : 0;
        s += v[i];
    }
    sh[t] = s;
    __syncthreads();
    for (int off = 1; off < 256; off <<= 1) {
        int u = (t >= off) ? sh[t - off] : 0;
        __syncthreads();
        sh[t] += u;
        __syncthreads();
    }
    int run = (t == 0) ? 0 : sh[t - 1];
#pragma unroll
    for (int i = 0; i < CH8; i++) {
        int idx = base + i;
        if (idx < NB8) boff[idx] = run;
        run += v[i];
    }
    if (t == 255) rowp8[M8] = sh[255];
}

__global__ void k_rowp(const int* __restrict__ cnt8, const int* __restrict__ boff,
                       int* __restrict__ rowp8, int* __restrict__ cur8) {
    __shared__ int sh[256];
    int b = blockIdx.x, t = threadIdx.x;
    int idx = b * 256 + t;
    int v = (idx < M8) ? cnt8[idx] : 0;
    sh[t] = v;
    __syncthreads();
    for (int off = 1; off < 256; off <<= 1) {
        int u = (t >= off) ? sh[t - off] : 0;
        __syncthreads();
        sh[t] += u;
        __syncthreads();
    }
    if (idx < M8) {
        int excl = sh[t] - v + boff[b];
        rowp8[idx] = excl;
        cur8[idx]  = excl;
    }
}

__global__ void k_degf(const int* __restrict__ rowp8, float* __restrict__ degf) {
    int i = blockIdx.x * blockDim.x + threadIdx.x;
    if (i < N_NODES) degf[i] = (float)(rowp8[(i + 1) * SH] - rowp8[i * SH] + 1);
}

__global__ void k_fill(const int* __restrict__ src, const int* __restrict__ dst,
                       int* __restrict__ cur8, int2* __restrict__ colperm) {
    int e = blockIdx.x * blockDim.x + threadIdx.x;
    if (e < N_EDGES) {
        int pos = atomicAdd(&cur8[dst[e] * SH + (e & (SH - 1))], 1);
        colperm[pos] = make_int2(src[e], e);
    }
}

// ea[i] = sum of in-edge edge_attr rows (fp32, small)
__global__ __launch_bounds__(256, 8) void k_ea_agg(
    const float* __restrict__ edge_attr,
    const int* __restrict__ rowp8, const int2* __restrict__ colperm,
    float* __restrict__ ea) {
    int lane = threadIdx.x & 63, wid = threadIdx.x >> 6;
    int q = lane >> 2;
    int c = lane & 3;
    const float4* a4p = (const float4*)edge_attr;
    int gw = blockIdx.x * 4 + wid, nw = gridDim.x * 4;
    for (int i = gw; i < N_NODES; i += nw) {
        int beg = rowp8[i * SH], end = rowp8[(i + 1) * SH];
        float x0 = 0.f, x1 = 0.f, x2 = 0.f, x3 = 0.f;
        for (int p = beg; p < end; p += 64) {
            int m = end - p; if (m > 64) m = 64;
            int cidx = p + lane; if (cidx > end - 1) cidx = end - 1;
            int vj = colperm[cidx].y;
#pragma unroll
            for (int k = 0; k < 4; k++) {
                int e = __shfl(vj, 16 * k + q, 64);
                float4 v = make_float4(0.f, 0.f, 0.f, 0.f);
                if (16 * k + q < m) v = a4p[(size_t)e * 4 + c];
                x0 += v.x; x1 += v.y; x2 += v.z; x3 += v.w;
            }
        }
#pragma unroll
        for (int msk = 4; msk <= 32; msk <<= 1) {
            x0 += __shfl_xor(x0, msk, 64);
            x1 += __shfl_xor(x1, msk, 64);
            x2 += __shfl_xor(x2, msk, 64);
            x3 += __shfl_xor(x3, msk, 64);
        }
        if (lane < 4) ((float4*)ea)[i * 4 + c] = make_float4(x0, x1, x2, x3);
    }
}

// ---------------- h0/base (VALU, reads fp32 x once) ----------------
__global__ void k_h0base(const float* __restrict__ x, const float* __restrict__ ea,
                         const float* __restrict__ Wnh, const float* __restrict__ bnh,
                         const float* __restrict__ Wmh, const float* __restrict__ bmh,
                         __half* __restrict__ h0out16, __half* __restrict__ base16) {
    __shared__ __align__(16) float sx[4][FDIM];
    __shared__ __align__(16) float sea[4][EDIM];
    int lane = threadIdx.x & 63;
    int wid  = threadIdx.x >> 6;
    float wnh[FDIM], w3[EDIM];
#pragma unroll
    for (int m = 0; m < FDIM; m++) wnh[m] = Wnh[m * FDIM + lane];
    float csum = 0.f;
#pragma unroll
    for (int m = 0; m < EDIM; m++) {
        w3[m] = Wmh[(2 * FDIM + m) * FDIM + lane];
        csum += w3[m];
    }
    float bnhk = bnh[lane], bmhk = bmh[lane];
    int gw = blockIdx.x * 4 + wid;
    int nw = gridDim.x * 4;
    for (int i = gw; i < N_NODES; i += nw) {
        sx[wid][lane] = x[i * FDIM + lane];
        if (lane < EDIM) sea[wid][lane] = ea[i * EDIM + lane];
        float acc0 = bnhk, acc1 = 0.f, acc2 = 0.f, acc3 = 0.f;
        const float4* s4 = (const float4*)sx[wid];
#pragma unroll
        for (int m4 = 0; m4 < FDIM / 4; m4++) {
            float4 v = s4[m4];
            acc0 = fmaf(v.x, wnh[4 * m4 + 0], acc0);
            acc1 = fmaf(v.y, wnh[4 * m4 + 1], acc1);
            acc2 = fmaf(v.z, wnh[4 * m4 + 2], acc2);
            acc3 = fmaf(v.w, wnh[4 * m4 + 3], acc3);
        }
        float h0 = fmaxf((acc0 + acc2) + (acc1 + acc3), 0.f);
        float b0 = h0 + bmhk + csum, b1 = 0.f, b2 = 0.f, b3 = 0.f;
        const float4* e4 = (const float4*)sea[wid];
#pragma unroll
        for (int m4 = 0; m4 < EDIM / 4; m4++) {
            float4 v = e4[m4];
            b0 = fmaf(v.x, w3[4 * m4 + 0], b0);
            b1 = fmaf(v.y, w3[4 * m4 + 1], b1);
            b2 = fmaf(v.z, w3[4 * m4 + 2], b2);
            b3 = fmaf(v.w, w3[4 * m4 + 3], b3);
        }
        h0out16[i * FDIM + lane] = __float2half(h0);
        base16[i * FDIM + lane]  = __float2half((b0 + b2) + (b1 + b3));
    }
}

// ---------------- fused gather + MFMA kernels ----------------
// Wave = one 16-node tile. Gather each node's neighbor sum into registers
// (8 lanes/row, 8 rows in flight), stage s2/s1 into per-wave LDS (no
// barriers), then 16-MFMA matvec + epilogue. agg16 round-trip eliminated.
#define SROW  136
#define SROW2 72

// whole-wave gather of one node's neighbor row-sum; result in a0..a7 (all lanes)
__device__ __forceinline__ void gather_node(const uint4* __restrict__ h8,
                                            const int2* __restrict__ colperm,
                                            int beg, int end, int lane, int q, int c,
                                            float& a0, float& a1, float& a2, float& a3,
                                            float& a4, float& a5, float& a6, float& a7) {
    a0 = a1 = a2 = a3 = a4 = a5 = a6 = a7 = 0.f;
    for (int p = beg; p < end; p += 64) {
        int m = end - p; if (m > 64) m = 64;
        int cidx = p + lane; if (cidx > end - 1) cidx = end - 1;
        int vj = colperm[cidx].x;
#pragma unroll
        for (int k = 0; k < 8; k++) {
            int j = __shfl(vj, 8 * k + q, 64);
            uint4 v = make_uint4(0, 0, 0, 0);
            if (8 * k + q < m) v = h8[(size_t)j * 8 + c];
            float2 f0 = __half22float2(__builtin_bit_cast(__half2, v.x));
            float2 f1 = __half22float2(__builtin_bit_cast(__half2, v.y));
            float2 f2 = __half22float2(__builtin_bit_cast(__half2, v.z));
            float2 f3 = __half22float2(__builtin_bit_cast(__half2, v.w));
            a0 += f0.x; a1 += f0.y; a2 += f1.x; a3 += f1.y;
            a4 += f2.x; a5 += f2.y; a6 += f3.x; a7 += f3.y;
        }
    }
#pragma unroll
    for (int msk = 8; msk <= 32; msk <<= 1) {
        a0 += __shfl_xor(a0, msk, 64); a1 += __shfl_xor(a1, msk, 64);
        a2 += __shfl_xor(a2, msk, 64); a3 += __shfl_xor(a3, msk, 64);
        a4 += __shfl_xor(a4, msk, 64); a5 += __shfl_xor(a5, msk, 64);
        a6 += __shfl_xor(a6, msk, 64); a7 += __shfl_xor(a7, msk, 64);
    }
}

// h_out = relu( (deg*h)@W1 + (Ah+h)@W2 + base )
__global__ __launch_bounds__(256, 4) void k_gmv_layer(
    const __half* __restrict__ hin16,
    const int* __restrict__ rowp8, const int2* __restrict__ colperm,
    const __half* __restrict__ base16, const float* __restrict__ degf,
    const float* __restrict__ Wmh, __half* __restrict__ hout16) {
    __shared__ __align__(16) _Float16 S[4][16 * SROW];
    int lane = threadIdx.x & 63, wid = threadIdx.x >> 6;
    int n = lane & 15, quad = lane >> 4;
    int q = lane >> 3, c = lane & 7;
    half8 bfr[4][4];
#pragma unroll
    for (int kk = 0; kk < 4; kk++)
#pragma unroll
        for (int nn = 0; nn < 4; nn++) {
            half8 tmp;
#pragma unroll
            for (int j = 0; j < 8; j++) {
                int kp = kk * 32 + quad * 8 + j;
                int krow = (kp < 64) ? (64 + kp) : (kp - 64);
                tmp[j] = (_Float16)Wmh[krow * FDIM + nn * 16 + n];
            }
            bfr[kk][nn] = tmp;
        }
    int t = blockIdx.x * 4 + wid;
    if (t >= NT) return;
    int tb = t * 16;
    const uint4* h8 = (const uint4*)hin16;
    uint4* Sw = (uint4*)(&S[wid][0]);
    for (int m = 0; m < 16; m++) {
        int node = tb + m;
        int beg = rowp8[node * SH], end = rowp8[(node + 1) * SH];
        float a0, a1, a2, a3, a4, a5, a6, a7;
        gather_node(h8, colperm, beg, end, lane, q, c, a0, a1, a2, a3, a4, a5, a6, a7);
        if (lane < 8) {
            uint4 hs = h8[(size_t)node * 8 + c];
            float2 h0f = __half22float2(__builtin_bit_cast(__half2, hs.x));
            float2 h1f = __half22float2(__builtin_bit_cast(__half2, hs.y));
            float2 h2f = __half22float2(__builtin_bit_cast(__half2, hs.z));
            float2 h3f = __half22float2(__builtin_bit_cast(__half2, hs.w));
            float dg = degf[node];
            uint4 s2, s1;
            s2.x = __builtin_bit_cast(unsigned, __floats2half2_rn(a0 + h0f.x, a1 + h0f.y));
            s2.y = __builtin_bit_cast(unsigned, __floats2half2_rn(a2 + h1f.x, a3 + h1f.y));
            s2.z = __builtin_bit_cast(unsigned, __floats2half2_rn(a4 + h2f.x, a5 + h2f.y));
            s2.w = __builtin_bit_cast(unsigned, __floats2half2_rn(a6 + h3f.x, a7 + h3f.y));
            s1.x = __builtin_bit_cast(unsigned, __floats2half2_rn(dg * h0f.x, dg * h0f.y));
            s1.y = __builtin_bit_cast(unsigned, __floats2half2_rn(dg * h1f.x, dg * h1f.y));
            s1.z = __builtin_bit_cast(unsigned, __floats2half2_rn(dg * h2f.x, dg * h2f.y));
            s1.w = __builtin_bit_cast(unsigned, __floats2half2_rn(dg * h3f.x, dg * h3f.y));
            Sw[m * (SROW / 8) + c]     = s2;   // SROW/8 = 17 uint4 slots per row
            Sw[m * (SROW / 8) + 8 + c] = s1;
        }
    }
    float4v acc[4];
#pragma unroll
    for (int nn = 0; nn < 4; nn++)
#pragma unroll
        for (int r = 0; r < 4; r++)
            acc[nn][r] = __half2float(base16[(size_t)(tb + quad * 4 + r) * FDIM + nn * 16 + n]);
    const _Float16* Sr = S[wid];
#pragma unroll
    for (int kk = 0; kk < 4; kk++) {
        half8 a = *(const half8*)(Sr + n * SROW + kk * 32 + quad * 8);
#pragma unroll
        for (int nn = 0; nn < 4; nn++)
            acc[nn] = __builtin_amdgcn_mfma_f32_16x16x32_f16(a, bfr[kk][nn], acc[nn], 0, 0, 0);
    }
#pragma unroll
    for (int nn = 0; nn < 4; nn++)
#pragma unroll
        for (int r = 0; r < 4; r++)
            hout16[(size_t)(tb + quad * 4 + r) * FDIM + nn * 16 + n] =
                __float2half(fmaxf(acc[nn][r], 0.f));
}

// sc[i] = relu( (deg*h)@Wom1 + (Ah+h)@Wom2 + obase ) . Wout
__global__ __launch_bounds__(256, 4) void k_gmv_out(
    const __half* __restrict__ hin16,
    const int* __restrict__ rowp8, const int2* __restrict__ colperm,
    const __half* __restrict__ obase16, const float* __restrict__ degf,
    const float* __restrict__ Wom, const float* __restrict__ Wout,
    float* __restrict__ sc) {
    __shared__ __align__(16) _Float16 S[4][16 * SROW];
    int lane = threadIdx.x & 63, wid = threadIdx.x >> 6;
    int n = lane & 15, quad = lane >> 4;
    int q = lane >> 3, c = lane & 7;
    half8 bfr[4][4];
#pragma unroll
    for (int kk = 0; kk < 4; kk++)
#pragma unroll
        for (int nn = 0; nn < 4; nn++) {
            half8 tmp;
#pragma unroll
            for (int j = 0; j < 8; j++) {
                int kp = kk * 32 + quad * 8 + j;
                int krow = (kp < 64) ? (64 + kp) : (kp - 64);
                tmp[j] = (_Float16)Wom[krow * FDIM + nn * 16 + n];
            }
            bfr[kk][nn] = tmp;
        }
    float wo0 = Wout[n], wo1 = Wout[16 + n], wo2 = Wout[32 + n], wo3 = Wout[48 + n];
    int t = blockIdx.x * 4 + wid;
    if (t >= NT) return;
    int tb = t * 16;
    const uint4* h8 = (const uint4*)hin16;
    uint4* Sw = (uint4*)(&S[wid][0]);
    for (int m = 0; m < 16; m++) {
        int node = tb + m;
        int beg = rowp8[node * SH], end = rowp8[(node + 1) * SH];
        float a0, a1, a2, a3, a4, a5, a6, a7;
        gather_node(h8, colperm, beg, end, lane, q, c, a0, a1, a2, a3, a4, a5, a6, a7);
        if (lane < 8) {
            uint4 hs = h8[(size_t)node * 8 + c];
            float2 h0f = __half22float2(__builtin_bit_cast(__half2, hs.x));
            float2 h1f = __half22float2(__builtin_bit_cast(__half2, hs.y));
            float2 h2f = __half22float2(__builtin_bit_cast(__half2, hs.z));
            float2 h3f = __half22float2(__builtin_bit_cast(__half2, hs.w));
            float dg = degf[node];
            uint4 s2, s1;
            s2.x = __builtin_bit_cast(unsigned, __floats2half2_rn(a0 + h0f.x, a1 + h0f.y));
            s2.y = __builtin_bit_cast(unsigned, __floats2half2_rn(a2 + h1f.x, a3 + h1f.y));
            s2.z = __builtin_bit_cast(unsigned, __floats2half2_rn(a4 + h2f.x, a5 + h2f.y));
            s2.w = __builtin_bit_cast(unsigned, __floats2half2_rn(a6 + h3f.x, a7 + h3f.y));
            s1.x = __builtin_bit_cast(unsigned, __floats2half2_rn(dg * h0f.x, dg * h0f.y));
            s1.y = __builtin_bit_cast(unsigned, __floats2half2_rn(dg * h1f.x, dg * h1f.y));
            s1.z = __builtin_bit_cast(unsigned, __floats2half2_rn(dg * h2f.x, dg * h2f.y));
            s1.w = __builtin_bit_cast(unsigned, __floats2half2_rn(dg * h3f.x, dg * h3f.y));
            Sw[m * (SROW / 8) + c]     = s2;
            Sw[m * (SROW / 8) + 8 + c] = s1;
        }
    }
    float4v acc[4];
#pragma unroll
    for (int nn = 0; nn < 4; nn++)
#pragma unroll
        for (int r = 0; r < 4; r++)
            acc[nn][r] = __half2float(obase16[(size_t)(tb + quad * 4 + r) * FDIM + nn * 16 + n]);
    const _Float16* Sr = S[wid];
#pragma unroll
    for (int kk = 0; kk < 4; kk++) {
        half8 a = *(const half8*)(Sr + n * SROW + kk * 32 + quad * 8);
#pragma unroll
        for (int nn = 0; nn < 4; nn++)
            acc[nn] = __builtin_amdgcn_mfma_f32_16x16x32_f16(a, bfr[kk][nn], acc[nn], 0, 0, 0);
    }
#pragma unroll
    for (int r = 0; r < 4; r++) {
        float s = fmaxf(acc[0][r], 0.f) * wo0 + fmaxf(acc[1][r], 0.f) * wo1
                + fmaxf(acc[2][r], 0.f) * wo2 + fmaxf(acc[3][r], 0.f) * wo3;
        s += __shfl_xor(s, 1, 64);
        s += __shfl_xor(s, 2, 64);
        s += __shfl_xor(s, 4, 64);
        s += __shfl_xor(s, 8, 64);
        if (n == 0) sc[tb + quad * 4 + r] = s;
    }
}

// obase = (Ax + x) @ Wom[128:192] + bom   (K=64, 8 MFMAs)
__global__ __launch_bounds__(256, 4) void k_gmv_obase(
    const __half* __restrict__ x16,
    const int* __restrict__ rowp8, const int2* __restrict__ colperm,
    const float* __restrict__ Wom, const float* __restrict__ bom,
    __half* __restrict__ obase16) {
    __shared__ __align__(16) _Float16 S[4][16 * SROW2];
    int lane = threadIdx.x & 63, wid = threadIdx.x >> 6;
    int n = lane & 15, quad = lane >> 4;
    int q = lane >> 3, c = lane & 7;
    half8 bfr[2][4];
#pragma unroll
    for (int kk = 0; kk < 2; kk++)
#pragma unroll
        for (int nn = 0; nn < 4; nn++) {
            half8 tmp;
#pragma unroll
            for (int j = 0; j < 8; j++) {
                int kp = kk * 32 + quad * 8 + j;
                tmp[j] = (_Float16)Wom[(128 + kp) * FDIM + nn * 16 + n];
            }
            bfr[kk][nn] = tmp;
        }
    float bom_n[4];
#pragma unroll
    for (int nn = 0; nn < 4; nn++) bom_n[nn] = bom[nn * 16 + n];
    int t = blockIdx.x * 4 + wid;
    if (t >= NT) return;
    int tb = t * 16;
    const uint4* h8 = (const uint4*)x16;
    uint4* Sw = (uint4*)(&S[wid][0]);
    for (int m = 0; m < 16; m++) {
        int node = tb + m;
        int beg = rowp8[node * SH], end = rowp8[(node + 1) * SH];
        float a0, a1, a2, a3, a4, a5, a6, a7;
        gather_node(h8, colperm, beg, end, lane, q, c, a0, a1, a2, a3, a4, a5, a6, a7);
        if (lane < 8) {
            uint4 hs = h8[(size_t)node * 8 + c];
            uint4 s2;
            s2.x = hadd2u(__builtin_bit_cast(unsigned, __floats2half2_rn(a0, a1)), hs.x);
            s2.y = hadd2u(__builtin_bit_cast(unsigned, __floats2half2_rn(a2, a3)), hs.y);
            s2.z = hadd2u(__builtin_bit_cast(unsigned, __floats2half2_rn(a4, a5)), hs.z);
            s2.w = hadd2u(__builtin_bit_cast(unsigned, __floats2half2_rn(a6, a7)), hs.w);
            Sw[m * (SROW2 / 8) + c] = s2;   // SROW2/8 = 9 slots per row
        }
    }
    float4v acc[4];
#pragma unroll
    for (int nn = 0; nn < 4; nn++)
#pragma unroll
        for (int r = 0; r < 4; r++) acc[nn][r] = bom_n[nn];
    const _Float16* Sr = S[wid];
#pragma unroll
    for (int kk = 0; kk < 2; kk++) {
        half8 a = *(const half8*)(Sr + n * SROW2 + kk * 32 + quad * 8);
#pragma unroll
        for (int nn = 0; nn < 4; nn++)
            acc[nn] = __builtin_amdgcn_mfma_f32_16x16x32_f16(a, bfr[kk][nn], acc[nn], 0, 0, 0);
    }
#pragma unroll
    for (int nn = 0; nn < 4; nn++)
#pragma unroll
        for (int r = 0; r < 4; r++)
            obase16[(size_t)(tb + quad * 4 + r) * FDIM + nn * 16 + n] =
                __float2half(acc[nn][r]);
}

// out[g] = sum of sc over graph-g nodes + b_out
__global__ void k_pool(const float* __restrict__ sc, const int* __restrict__ batch,
                       const float* __restrict__ b_out, float* __restrict__ out) {
    __shared__ float red[4];
    int g = blockIdx.x, t = threadIdx.x;
    int lo = 0, hi = N_NODES;
    while (lo < hi) { int mid = (lo + hi) >> 1; if (batch[mid] < g) lo = mid + 1; else hi = mid; }
    int lo2 = lo, hi2 = N_NODES;
    while (lo2 < hi2) { int mid = (lo2 + hi2) >> 1; if (batch[mid] < g + 1) lo2 = mid + 1; else hi2 = mid; }
    float s = 0.f;
    for (int i = lo + t; i < lo2; i += 256) s += sc[i];
#pragma unroll
    for (int off = 32; off > 0; off >>= 1) s += __shfl_down(s, off, 64);
    int lane = t & 63, wid = t >> 6;
    if (lane == 0) red[wid] = s;
    __syncthreads();
    if (t == 0) out[g] = red[0] + red[1] + red[2] + red[3] + b_out[0];
}

// ---------------- launcher ----------------

extern "C" void kernel_launch(void* const* d_in, const int* in_sizes, int n_in,
                              void* d_out, int out_size, void* d_ws, size_t ws_size,
                              hipStream_t stream) {
    const float* x         = (const float*)d_in[0];
    const float* edge_attr = (const float*)d_in[1];
    const float* Wnh       = (const float*)d_in[2];
    const float* bnh       = (const float*)d_in[3];
    const float* Wmh       = (const float*)d_in[4];
    const float* bmh       = (const float*)d_in[5];
    const float* Wom       = (const float*)d_in[6];
    const float* bom       = (const float*)d_in[7];
    const float* Wout      = (const float*)d_in[8];
    const float* bout      = (const float*)d_in[9];
    const int*   eidx      = (const int*)d_in[10];
    const int*   batch     = (const int*)d_in[11];
    const int*   srcI = eidx;
    const int*   dstI = eidx + N_EDGES;
    float* out = (float*)d_out;
    (void)in_sizes; (void)n_in; (void)out_size;

    char* w = (char*)d_ws;
    size_t off = 0;
    auto take = [&](size_t b) -> void* {
        void* p = w + off;
        off = (off + b + 255) & ~(size_t)255;
        return p;
    };
    float*  ea     = (float*)take((size_t)N_NODES * EDIM * 4);
    int*    cnt8   = (int*)take((size_t)M8 * 4);
    int*    rowp8  = (int*)take((size_t)(M8 + 1) * 4);
    int*    cur8   = (int*)take((size_t)M8 * 4);
    float*  degf   = (float*)take((size_t)N_NODES * 4);
    int2*   colperm= (int2*)take((size_t)N_EDGES * 8);
    float*  sc     = (float*)take((size_t)N_NODES * 4);
    int*    blks   = (int*)take((size_t)NB8 * 4);
    int*    boff   = (int*)take((size_t)NB8 * 4);
    __half* x16    = (__half*)take((size_t)N_NODES * FDIM * 2);
    __half* hA16   = (__half*)take((size_t)N_NODES * FDIM * 2);
    __half* hB16   = (__half*)take((size_t)N_NODES * FDIM * 2);
    __half* base16 = (__half*)take((size_t)N_NODES * FDIM * 2);
    __half* obase16= (__half*)take((size_t)N_NODES * FDIM * 2);
    (void)ws_size;

    const int MVG = (NT + 3) / 4;   // 782 blocks, 1 tile per wave

    hipMemsetAsync(cnt8, 0, (size_t)M8 * 4, stream);
    k_count<<<(N_EDGES + 255) / 256, 256, 0, stream>>>(dstI, cnt8);
    k_cvt_x<<<(N_NODES * FDIM + 255) / 256, 256, 0, stream>>>(x, x16);
    k_blksum<<<NB8, 256, 0, stream>>>(cnt8, blks);
    k_scanblk<<<1, 256, 0, stream>>>(blks, boff, rowp8);
    k_rowp<<<NB8, 256, 0, stream>>>(cnt8, boff, rowp8, cur8);
    k_degf<<<(N_NODES + 255) / 256, 256, 0, stream>>>(rowp8, degf);
    k_fill<<<(N_EDGES + 255) / 256, 256, 0, stream>>>(srcI, dstI, cur8, colperm);

    k_gmv_obase<<<MVG, 256, 0, stream>>>(x16, rowp8, colperm, Wom, bom, obase16);
    k_ea_agg<<<2048, 256, 0, stream>>>(edge_attr, rowp8, colperm, ea);
    k_h0base<<<2048, 256, 0, stream>>>(x, ea, Wnh, bnh, Wmh, bmh, hA16, base16);

    k_gmv_layer<<<MVG, 256, 0, stream>>>(hA16, rowp8, colperm, base16, degf, Wmh, hB16);
    k_gmv_layer<<<MVG, 256, 0, stream>>>(hB16, rowp8, colperm, base16, degf, Wmh, hA16);
    k_gmv_layer<<<MVG, 256, 0, stream>>>(hA16, rowp8, colperm, base16, degf, Wmh, hB16);
    k_gmv_out<<<MVG, 256, 0, stream>>>(hB16, rowp8, colperm, obase16, degf, Wom, Wout, sc);
    k_pool<<<NGRAPH, 256, 0, stream>>>(sc, batch, bout, out);
}

// Round 12
// 393.160 us; speedup vs baseline: 1.5382x; 1.5382x over previous
//
#include <hip/hip_runtime.h>
#include <hip/hip_fp16.h>

#define N_NODES 50000
#define N_EDGES 800000
#define NGRAPH  256
#define FDIM    64
#define EDIM    16
#define NT      (N_NODES / 16)      // 3125 node tiles (exact)
#define SH      8                   // CSR counter shards
#define M8      (N_NODES * SH)
#define NB8     ((M8 + 255) / 256)
#define CH8     ((NB8 + 255) / 256)
#define NBG     ((N_NODES + 31) / 32)   // gather blocks: 32 nodes/block (8/wave)

using half8  = __attribute__((ext_vector_type(8))) _Float16;
using float4v = __attribute__((ext_vector_type(4))) float;

__device__ __forceinline__ unsigned hadd2u(unsigned a, unsigned b) {
    __half2 r = __hadd2(__builtin_bit_cast(__half2, a), __builtin_bit_cast(__half2, b));
    return __builtin_bit_cast(unsigned, r);
}
__device__ __forceinline__ unsigned hmul2u(unsigned a, __half2 m) {
    __half2 r = __hmul2(__builtin_bit_cast(__half2, a), m);
    return __builtin_bit_cast(unsigned, r);
}

// ---------------- small setup kernels ----------------

__global__ void k_count(const int* __restrict__ dst, int* __restrict__ cnt8) {
    int e = blockIdx.x * blockDim.x + threadIdx.x;
    if (e < N_EDGES) atomicAdd(&cnt8[dst[e] * SH + (e & (SH - 1))], 1);
}

__global__ void k_cvt_x(const float* __restrict__ x, __half* __restrict__ x16) {
    int t = blockIdx.x * blockDim.x + threadIdx.x;
    if (t < N_NODES * FDIM) x16[t] = __float2half(x[t]);
}

__global__ void k_blksum(const int* __restrict__ cnt8, int* __restrict__ blksum) {
    __shared__ int red[4];
    int b = blockIdx.x, t = threadIdx.x;
    int idx = b * 256 + t;
    int s = (idx < M8) ? cnt8[idx] : 0;
#pragma unroll
    for (int off = 32; off > 0; off >>= 1) s += __shfl_down(s, off, 64);
    int lane = t & 63, wid = t >> 6;
    if (lane == 0) red[wid] = s;
    __syncthreads();
    if (t == 0) blksum[b] = red[0] + red[1] + red[2] + red[3];
}

__global__ void k_scanblk(const int* __restrict__ blksum, int* __restrict__ boff,
                          int* __restrict__ rowp8) {
    __shared__ int sh[256];
    int t = threadIdx.x;
    int base = t * CH8;
    int v[CH8];
    int s = 0;
#pragma unroll
    for (int i = 0; i < CH8; i++) {
        int idx = base + i;
        v[i] = (idx < NB8) ? blksum[idx] : 0;
        s += v[i];
    }
    sh[t] = s;
    __syncthreads();
    for (int off = 1; off < 256; off <<= 1) {
        int u = (t >= off) ? sh[t - off] : 0;
        __syncthreads();
        sh[t] += u;
        __syncthreads();
    }
    int run = (t == 0) ? 0 : sh[t - 1];
#pragma unroll
    for (int i = 0; i < CH8; i++) {
        int idx = base + i;
        if (idx < NB8) boff[idx] = run;
        run += v[i];
    }
    if (t == 255) rowp8[M8] = sh[255];
}

__global__ void k_rowp(const int* __restrict__ cnt8, const int* __restrict__ boff,
                       int* __restrict__ rowp8, int* __restrict__ cur8) {
    __shared__ int sh[256];
    int b = blockIdx.x, t = threadIdx.x;
    int idx = b * 256 + t;
    int v = (idx < M8) ? cnt8[idx] : 0;
    sh[t] = v;
    __syncthreads();
    for (int off = 1; off < 256; off <<= 1) {
        int u = (t >= off) ? sh[t - off] : 0;
        __syncthreads();
        sh[t] += u;
        __syncthreads();
    }
    if (idx < M8) {
        int excl = sh[t] - v + boff[b];
        rowp8[idx] = excl;
        cur8[idx]  = excl;
    }
}

__global__ void k_degf(const int* __restrict__ rowp8, float* __restrict__ degf) {
    int i = blockIdx.x * blockDim.x + threadIdx.x;
    if (i < N_NODES) degf[i] = (float)(rowp8[(i + 1) * SH] - rowp8[i * SH] + 1);
}

__global__ void k_fill(const int* __restrict__ src, const int* __restrict__ dst,
                       int* __restrict__ cur8, int2* __restrict__ colperm) {
    int e = blockIdx.x * blockDim.x + threadIdx.x;
    if (e < N_EDGES) {
        int pos = atomicAdd(&cur8[dst[e] * SH + (e & (SH - 1))], 1);
        colperm[pos] = make_int2(src[e], e);
    }
}

// ---------------- subgroup-per-node gathers ----------------
// Each 8-lane subgroup owns ONE node. Lane c accumulates feature slot c
// across all the node's edges -> NO cross-lane reduction; 8 independent
// row-loads per chunk per subgroup -> 64 rows in flight per wave.

// agg16[i] = sum_{j in-nbrs} h16[j]   (row = 8 x uint4)
__global__ __launch_bounds__(256, 8) void k_gather(
    const __half* __restrict__ h16,
    const int* __restrict__ rowp8, const int2* __restrict__ colperm,
    __half* __restrict__ agg16) {
    int lane = threadIdx.x & 63, wid = threadIdx.x >> 6;
    int g = lane >> 3;   // subgroup = node slot
    int c = lane & 7;    // uint4 slot within row
    const uint4* h8 = (const uint4*)h16;
    int node = (blockIdx.x * 4 + wid) * 8 + g;
    if (node >= N_NODES) return;
    int beg = rowp8[node * SH], end = rowp8[(node + 1) * SH];
    float a0 = 0, a1 = 0, a2 = 0, a3 = 0, a4 = 0, a5 = 0, a6 = 0, a7 = 0;
    for (int p = beg; p < end; p += 8) {
        int cidx = p + c; if (cidx > end - 1) cidx = end - 1;
        int vj = colperm[cidx].x;
#pragma unroll
        for (int k = 0; k < 8; k++) {
            int j = __shfl(vj, g * 8 + k, 64);
            if (p + k < end) {
                uint4 v = h8[(size_t)j * 8 + c];
                float2 f0 = __half22float2(__builtin_bit_cast(__half2, v.x));
                float2 f1 = __half22float2(__builtin_bit_cast(__half2, v.y));
                float2 f2 = __half22float2(__builtin_bit_cast(__half2, v.z));
                float2 f3 = __half22float2(__builtin_bit_cast(__half2, v.w));
                a0 += f0.x; a1 += f0.y; a2 += f1.x; a3 += f1.y;
                a4 += f2.x; a5 += f2.y; a6 += f3.x; a7 += f3.y;
            }
        }
    }
    uint4 o;
    o.x = __builtin_bit_cast(unsigned, __floats2half2_rn(a0, a1));
    o.y = __builtin_bit_cast(unsigned, __floats2half2_rn(a2, a3));
    o.z = __builtin_bit_cast(unsigned, __floats2half2_rn(a4, a5));
    o.w = __builtin_bit_cast(unsigned, __floats2half2_rn(a6, a7));
    ((uint4*)agg16)[(size_t)node * 8 + c] = o;
}

// ea[i] = sum of in-edge edge_attr rows (row = 8 x float2)
__global__ __launch_bounds__(256, 8) void k_ea_agg(
    const float* __restrict__ edge_attr,
    const int* __restrict__ rowp8, const int2* __restrict__ colperm,
    float* __restrict__ ea) {
    int lane = threadIdx.x & 63, wid = threadIdx.x >> 6;
    int g = lane >> 3;
    int c = lane & 7;
    const float2* a2p = (const float2*)edge_attr;  // row = 8 float2
    int node = (blockIdx.x * 4 + wid) * 8 + g;
    if (node >= N_NODES) return;
    int beg = rowp8[node * SH], end = rowp8[(node + 1) * SH];
    float x0 = 0.f, x1 = 0.f;
    for (int p = beg; p < end; p += 8) {
        int cidx = p + c; if (cidx > end - 1) cidx = end - 1;
        int vj = colperm[cidx].y;
#pragma unroll
        for (int k = 0; k < 8; k++) {
            int e = __shfl(vj, g * 8 + k, 64);
            if (p + k < end) {
                float2 v = a2p[(size_t)e * 8 + c];
                x0 += v.x; x1 += v.y;
            }
        }
    }
    ((float2*)ea)[(size_t)node * 8 + c] = make_float2(x0, x1);
}

// ---------------- h0/base (VALU, reads fp32 x once) ----------------
__global__ void k_h0base(const float* __restrict__ x, const float* __restrict__ ea,
                         const float* __restrict__ Wnh, const float* __restrict__ bnh,
                         const float* __restrict__ Wmh, const float* __restrict__ bmh,
                         __half* __restrict__ h0out16, __half* __restrict__ base16) {
    __shared__ __align__(16) float sx[4][FDIM];
    __shared__ __align__(16) float sea[4][EDIM];
    int lane = threadIdx.x & 63;
    int wid  = threadIdx.x >> 6;
    float wnh[FDIM], w3[EDIM];
#pragma unroll
    for (int m = 0; m < FDIM; m++) wnh[m] = Wnh[m * FDIM + lane];
    float csum = 0.f;
#pragma unroll
    for (int m = 0; m < EDIM; m++) {
        w3[m] = Wmh[(2 * FDIM + m) * FDIM + lane];
        csum += w3[m];
    }
    float bnhk = bnh[lane], bmhk = bmh[lane];
    int gw = blockIdx.x * 4 + wid;
    int nw = gridDim.x * 4;
    for (int i = gw; i < N_NODES; i += nw) {
        sx[wid][lane] = x[i * FDIM + lane];
        if (lane < EDIM) sea[wid][lane] = ea[i * EDIM + lane];
        float acc0 = bnhk, acc1 = 0.f, acc2 = 0.f, acc3 = 0.f;
        const float4* s4 = (const float4*)sx[wid];
#pragma unroll
        for (int m4 = 0; m4 < FDIM / 4; m4++) {
            float4 v = s4[m4];
            acc0 = fmaf(v.x, wnh[4 * m4 + 0], acc0);
            acc1 = fmaf(v.y, wnh[4 * m4 + 1], acc1);
            acc2 = fmaf(v.z, wnh[4 * m4 + 2], acc2);
            acc3 = fmaf(v.w, wnh[4 * m4 + 3], acc3);
        }
        float h0 = fmaxf((acc0 + acc2) + (acc1 + acc3), 0.f);
        float b0 = h0 + bmhk + csum, b1 = 0.f, b2 = 0.f, b3 = 0.f;
        const float4* e4 = (const float4*)sea[wid];
#pragma unroll
        for (int m4 = 0; m4 < EDIM / 4; m4++) {
            float4 v = e4[m4];
            b0 = fmaf(v.x, w3[4 * m4 + 0], b0);
            b1 = fmaf(v.y, w3[4 * m4 + 1], b1);
            b2 = fmaf(v.z, w3[4 * m4 + 2], b2);
            b3 = fmaf(v.w, w3[4 * m4 + 3], b3);
        }
        h0out16[i * FDIM + lane] = __float2half(h0);
        base16[i * FDIM + lane]  = __float2half((b0 + b2) + (b1 + b3));
    }
}

// ---------------- MFMA mv kernels (unchanged from R10) ----------------
#define SROW 136

__global__ __launch_bounds__(256, 4) void k_mv_mfma(
    const __half* __restrict__ agg16, const __half* __restrict__ hin16,
    const __half* __restrict__ base16, const float* __restrict__ degf,
    const float* __restrict__ Wmh, __half* __restrict__ hout16) {
    __shared__ __align__(16) _Float16 S[4][16 * SROW];
    int lane = threadIdx.x & 63, wid = threadIdx.x >> 6;
    int n = lane & 15, quad = lane >> 4;
    half8 bfr[4][4];
#pragma unroll
    for (int kk = 0; kk < 4; kk++)
#pragma unroll
        for (int nn = 0; nn < 4; nn++) {
            half8 tmp;
#pragma unroll
            for (int j = 0; j < 8; j++) {
                int kp = kk * 32 + quad * 8 + j;
                int krow = (kp < 64) ? (64 + kp) : (kp - 64);
                tmp[j] = (_Float16)Wmh[krow * FDIM + nn * 16 + n];
            }
            bfr[kk][nn] = tmp;
        }
    int t = blockIdx.x * 4 + wid;
    if (t >= NT) return;
    int tb = t * 16;
    {
        int m = lane >> 2, c = lane & 3;
        int node = tb + m;
        const uint4* ag4 = (const uint4*)agg16;
        const uint4* hh4 = (const uint4*)hin16;
        uint4 agA = ag4[(size_t)node * 8 + c * 2];
        uint4 agB = ag4[(size_t)node * 8 + c * 2 + 1];
        uint4 hA  = hh4[(size_t)node * 8 + c * 2];
        uint4 hB  = hh4[(size_t)node * 8 + c * 2 + 1];
        __half dh = __float2half(degf[node]);
        __half2 dh2 = __halves2half2(dh, dh);
        uint4 s2A, s2B, s1A, s1B;
        s2A.x = hadd2u(agA.x, hA.x); s2A.y = hadd2u(agA.y, hA.y);
        s2A.z = hadd2u(agA.z, hA.z); s2A.w = hadd2u(agA.w, hA.w);
        s2B.x = hadd2u(agB.x, hB.x); s2B.y = hadd2u(agB.y, hB.y);
        s2B.z = hadd2u(agB.z, hB.z); s2B.w = hadd2u(agB.w, hB.w);
        s1A.x = hmul2u(hA.x, dh2); s1A.y = hmul2u(hA.y, dh2);
        s1A.z = hmul2u(hA.z, dh2); s1A.w = hmul2u(hA.w, dh2);
        s1B.x = hmul2u(hB.x, dh2); s1B.y = hmul2u(hB.y, dh2);
        s1B.z = hmul2u(hB.z, dh2); s1B.w = hmul2u(hB.w, dh2);
        uint4* Sw = (uint4*)(&S[wid][m * SROW]);
        Sw[c * 2]     = s2A;
        Sw[c * 2 + 1] = s2B;
        Sw[8 + c * 2]     = s1A;
        Sw[8 + c * 2 + 1] = s1B;
    }
    float4v acc[4];
#pragma unroll
    for (int nn = 0; nn < 4; nn++)
#pragma unroll
        for (int r = 0; r < 4; r++)
            acc[nn][r] = __half2float(base16[(size_t)(tb + quad * 4 + r) * FDIM + nn * 16 + n]);
    const _Float16* Sr = S[wid];
#pragma unroll
    for (int kk = 0; kk < 4; kk++) {
        half8 a = *(const half8*)(Sr + (lane & 15) * SROW + kk * 32 + quad * 8);
#pragma unroll
        for (int nn = 0; nn < 4; nn++)
            acc[nn] = __builtin_amdgcn_mfma_f32_16x16x32_f16(a, bfr[kk][nn], acc[nn], 0, 0, 0);
    }
#pragma unroll
    for (int nn = 0; nn < 4; nn++)
#pragma unroll
        for (int r = 0; r < 4; r++)
            hout16[(size_t)(tb + quad * 4 + r) * FDIM + nn * 16 + n] =
                __float2half(fmaxf(acc[nn][r], 0.f));
}

__global__ __launch_bounds__(256, 4) void k_out_mv_mfma(
    const __half* __restrict__ agg16, const __half* __restrict__ hin16,
    const __half* __restrict__ obase16, const float* __restrict__ degf,
    const float* __restrict__ Wom, const float* __restrict__ Wout,
    float* __restrict__ sc) {
    __shared__ __align__(16) _Float16 S[4][16 * SROW];
    int lane = threadIdx.x & 63, wid = threadIdx.x >> 6;
    int n = lane & 15, quad = lane >> 4;
    half8 bfr[4][4];
#pragma unroll
    for (int kk = 0; kk < 4; kk++)
#pragma unroll
        for (int nn = 0; nn < 4; nn++) {
            half8 tmp;
#pragma unroll
            for (int j = 0; j < 8; j++) {
                int kp = kk * 32 + quad * 8 + j;
                int krow = (kp < 64) ? (64 + kp) : (kp - 64);
                tmp[j] = (_Float16)Wom[krow * FDIM + nn * 16 + n];
            }
            bfr[kk][nn] = tmp;
        }
    float wo0 = Wout[n], wo1 = Wout[16 + n], wo2 = Wout[32 + n], wo3 = Wout[48 + n];
    int t = blockIdx.x * 4 + wid;
    if (t >= NT) return;
    int tb = t * 16;
    {
        int m = lane >> 2, c = lane & 3;
        int node = tb + m;
        const uint4* ag4 = (const uint4*)agg16;
        const uint4* hh4 = (const uint4*)hin16;
        uint4 agA = ag4[(size_t)node * 8 + c * 2];
        uint4 agB = ag4[(size_t)node * 8 + c * 2 + 1];
        uint4 hA  = hh4[(size_t)node * 8 + c * 2];
        uint4 hB  = hh4[(size_t)node * 8 + c * 2 + 1];
        __half dh = __float2half(degf[node]);
        __half2 dh2 = __halves2half2(dh, dh);
        uint4 s2A, s2B, s1A, s1B;
        s2A.x = hadd2u(agA.x, hA.x); s2A.y = hadd2u(agA.y, hA.y);
        s2A.z = hadd2u(agA.z, hA.z); s2A.w = hadd2u(agA.w, hA.w);
        s2B.x = hadd2u(agB.x, hB.x); s2B.y = hadd2u(agB.y, hB.y);
        s2B.z = hadd2u(agB.z, hB.z); s2B.w = hadd2u(agB.w, hB.w);
        s1A.x = hmul2u(hA.x, dh2); s1A.y = hmul2u(hA.y, dh2);
        s1A.z = hmul2u(hA.z, dh2); s1A.w = hmul2u(hA.w, dh2);
        s1B.x = hmul2u(hB.x, dh2); s1B.y = hmul2u(hB.y, dh2);
        s1B.z = hmul2u(hB.z, dh2); s1B.w = hmul2u(hB.w, dh2);
        uint4* Sw = (uint4*)(&S[wid][m * SROW]);
        Sw[c * 2]     = s2A;
        Sw[c * 2 + 1] = s2B;
        Sw[8 + c * 2]     = s1A;
        Sw[8 + c * 2 + 1] = s1B;
    }
    float4v acc[4];
#pragma unroll
    for (int nn = 0; nn < 4; nn++)
#pragma unroll
        for (int r = 0; r < 4; r++)
            acc[nn][r] = __half2float(obase16[(size_t)(tb + quad * 4 + r) * FDIM + nn * 16 + n]);
    const _Float16* Sr = S[wid];
#pragma unroll
    for (int kk = 0; kk < 4; kk++) {
        half8 a = *(const half8*)(Sr + (lane & 15) * SROW + kk * 32 + quad * 8);
#pragma unroll
        for (int nn = 0; nn < 4; nn++)
            acc[nn] = __builtin_amdgcn_mfma_f32_16x16x32_f16(a, bfr[kk][nn], acc[nn], 0, 0, 0);
    }
#pragma unroll
    for (int r = 0; r < 4; r++) {
        float s = fmaxf(acc[0][r], 0.f) * wo0 + fmaxf(acc[1][r], 0.f) * wo1
                + fmaxf(acc[2][r], 0.f) * wo2 + fmaxf(acc[3][r], 0.f) * wo3;
        s += __shfl_xor(s, 1, 64);
        s += __shfl_xor(s, 2, 64);
        s += __shfl_xor(s, 4, 64);
        s += __shfl_xor(s, 8, 64);
        if (n == 0) sc[tb + quad * 4 + r] = s;
    }
}

// obase = (aggX + x) @ Wom[128:192] + bom   (K=64, 8 MFMAs)
#define SROW2 72
__global__ __launch_bounds__(256, 4) void k_obase_mfma(
    const __half* __restrict__ aggX16, const __half* __restrict__ x16,
    const float* __restrict__ Wom, const float* __restrict__ bom,
    __half* __restrict__ obase16) {
    __shared__ __align__(16) _Float16 S[4][16 * SROW2];
    int lane = threadIdx.x & 63, wid = threadIdx.x >> 6;
    int n = lane & 15, quad = lane >> 4;
    half8 bfr[2][4];
#pragma unroll
    for (int kk = 0; kk < 2; kk++)
#pragma unroll
        for (int nn = 0; nn < 4; nn++) {
            half8 tmp;
#pragma unroll
            for (int j = 0; j < 8; j++) {
                int kp = kk * 32 + quad * 8 + j;
                tmp[j] = (_Float16)Wom[(128 + kp) * FDIM + nn * 16 + n];
            }
            bfr[kk][nn] = tmp;
        }
    float bom_n[4];
#pragma unroll
    for (int nn = 0; nn < 4; nn++) bom_n[nn] = bom[nn * 16 + n];
    int t = blockIdx.x * 4 + wid;
    if (t >= NT) return;
    int tb = t * 16;
    {
        int m = lane >> 2, c = lane & 3;
        int node = tb + m;
        const uint4* ag4 = (const uint4*)aggX16;
        const uint4* xx4 = (const uint4*)x16;
        uint4 agA = ag4[(size_t)node * 8 + c * 2];
        uint4 agB = ag4[(size_t)node * 8 + c * 2 + 1];
        uint4 xA  = xx4[(size_t)node * 8 + c * 2];
        uint4 xB  = xx4[(size_t)node * 8 + c * 2 + 1];
        uint4 sA, sB;
        sA.x = hadd2u(agA.x, xA.x); sA.y = hadd2u(agA.y, xA.y);
        sA.z = hadd2u(agA.z, xA.z); sA.w = hadd2u(agA.w, xA.w);
        sB.x = hadd2u(agB.x, xB.x); sB.y = hadd2u(agB.y, xB.y);
        sB.z = hadd2u(agB.z, xB.z); sB.w = hadd2u(agB.w, xB.w);
        uint4* Sw = (uint4*)(&S[wid][m * SROW2]);
        Sw[c * 2]     = sA;
        Sw[c * 2 + 1] = sB;
    }
    float4v acc[4];
#pragma unroll
    for (int nn = 0; nn < 4; nn++)
#pragma unroll
        for (int r = 0; r < 4; r++) acc[nn][r] = bom_n[nn];
    const _Float16* Sr = S[wid];
#pragma unroll
    for (int kk = 0; kk < 2; kk++) {
        half8 a = *(const half8*)(Sr + (lane & 15) * SROW2 + kk * 32 + quad * 8);
#pragma unroll
        for (int nn = 0; nn < 4; nn++)
            acc[nn] = __builtin_amdgcn_mfma_f32_16x16x32_f16(a, bfr[kk][nn], acc[nn], 0, 0, 0);
    }
#pragma unroll
    for (int nn = 0; nn < 4; nn++)
#pragma unroll
        for (int r = 0; r < 4; r++)
            obase16[(size_t)(tb + quad * 4 + r) * FDIM + nn * 16 + n] =
                __float2half(acc[nn][r]);
}

// out[g] = sum of sc over graph-g nodes + b_out
__global__ void k_pool(const float* __restrict__ sc, const int* __restrict__ batch,
                       const float* __restrict__ b_out, float* __restrict__ out) {
    __shared__ float red[4];
    int g = blockIdx.x, t = threadIdx.x;
    int lo = 0, hi = N_NODES;
    while (lo < hi) { int mid = (lo + hi) >> 1; if (batch[mid] < g) lo = mid + 1; else hi = mid; }
    int lo2 = lo, hi2 = N_NODES;
    while (lo2 < hi2) { int mid = (lo2 + hi2) >> 1; if (batch[mid] < g + 1) lo2 = mid + 1; else hi2 = mid; }
    float s = 0.f;
    for (int i = lo + t; i < lo2; i += 256) s += sc[i];
#pragma unroll
    for (int off = 32; off > 0; off >>= 1) s += __shfl_down(s, off, 64);
    int lane = t & 63, wid = t >> 6;
    if (lane == 0) red[wid] = s;
    __syncthreads();
    if (t == 0) out[g] = red[0] + red[1] + red[2] + red[3] + b_out[0];
}

// ---------------- launcher ----------------

extern "C" void kernel_launch(void* const* d_in, const int* in_sizes, int n_in,
                              void* d_out, int out_size, void* d_ws, size_t ws_size,
                              hipStream_t stream) {
    const float* x         = (const float*)d_in[0];
    const float* edge_attr = (const float*)d_in[1];
    const float* Wnh       = (const float*)d_in[2];
    const float* bnh       = (const float*)d_in[3];
    const float* Wmh       = (const float*)d_in[4];
    const float* bmh       = (const float*)d_in[5];
    const float* Wom       = (const float*)d_in[6];
    const float* bom       = (const float*)d_in[7];
    const float* Wout      = (const float*)d_in[8];
    const float* bout      = (const float*)d_in[9];
    const int*   eidx      = (const int*)d_in[10];
    const int*   batch     = (const int*)d_in[11];
    const int*   srcI = eidx;
    const int*   dstI = eidx + N_EDGES;
    float* out = (float*)d_out;
    (void)in_sizes; (void)n_in; (void)out_size;

    char* w = (char*)d_ws;
    size_t off = 0;
    auto take = [&](size_t b) -> void* {
        void* p = w + off;
        off = (off + b + 255) & ~(size_t)255;
        return p;
    };
    float*  ea     = (float*)take((size_t)N_NODES * EDIM * 4);
    int*    cnt8   = (int*)take((size_t)M8 * 4);
    int*    rowp8  = (int*)take((size_t)(M8 + 1) * 4);
    int*    cur8   = (int*)take((size_t)M8 * 4);
    float*  degf   = (float*)take((size_t)N_NODES * 4);
    int2*   colperm= (int2*)take((size_t)N_EDGES * 8);
    float*  sc     = (float*)take((size_t)N_NODES * 4);
    int*    blks   = (int*)take((size_t)NB8 * 4);
    int*    boff   = (int*)take((size_t)NB8 * 4);
    __half* x16    = (__half*)take((size_t)N_NODES * FDIM * 2);
    __half* hA16   = (__half*)take((size_t)N_NODES * FDIM * 2);
    __half* hB16   = (__half*)take((size_t)N_NODES * FDIM * 2);
    __half* agg16  = (__half*)take((size_t)N_NODES * FDIM * 2);
    __half* base16 = (__half*)take((size_t)N_NODES * FDIM * 2);
    __half* obase16= (__half*)take((size_t)N_NODES * FDIM * 2);
    (void)ws_size;

    const int MVG = (NT + 3) / 4;
    const int GBG = (NBG + 0);   // gather grid: 32 nodes per block

    hipMemsetAsync(cnt8, 0, (size_t)M8 * 4, stream);
    k_count<<<(N_EDGES + 255) / 256, 256, 0, stream>>>(dstI, cnt8);
    k_cvt_x<<<(N_NODES * FDIM + 255) / 256, 256, 0, stream>>>(x, x16);
    k_blksum<<<NB8, 256, 0, stream>>>(cnt8, blks);
    k_scanblk<<<1, 256, 0, stream>>>(blks, boff, rowp8);
    k_rowp<<<NB8, 256, 0, stream>>>(cnt8, boff, rowp8, cur8);
    k_degf<<<(N_NODES + 255) / 256, 256, 0, stream>>>(rowp8, degf);
    k_fill<<<(N_EDGES + 255) / 256, 256, 0, stream>>>(srcI, dstI, cur8, colperm);

    k_gather<<<GBG, 256, 0, stream>>>(x16, rowp8, colperm, agg16);          // aggX
    k_obase_mfma<<<MVG, 256, 0, stream>>>(agg16, x16, Wom, bom, obase16);
    k_ea_agg<<<GBG, 256, 0, stream>>>(edge_attr, rowp8, colperm, ea);
    k_h0base<<<2048, 256, 0, stream>>>(x, ea, Wnh, bnh, Wmh, bmh, hA16, base16);

    k_gather<<<GBG, 256, 0, stream>>>(hA16, rowp8, colperm, agg16);
    k_mv_mfma<<<MVG, 256, 0, stream>>>(agg16, hA16, base16, degf, Wmh, hB16);

    k_gather<<<GBG, 256, 0, stream>>>(hB16, rowp8, colperm, agg16);
    k_mv_mfma<<<MVG, 256, 0, stream>>>(agg16, hB16, base16, degf, Wmh, hA16);

    k_gather<<<GBG, 256, 0, stream>>>(hA16, rowp8, colperm, agg16);
    k_mv_mfma<<<MVG, 256, 0, stream>>>(agg16, hA16, base16, degf, Wmh, hB16);

    k_gather<<<GBG, 256, 0, stream>>>(hB16, rowp8, colperm, agg16);
    k_out_mv_mfma<<<MVG, 256, 0, stream>>>(agg16, hB16, obase16, degf, Wom, Wout, sc);
    k_pool<<<NGRAPH, 256, 0, stream>>>(sc, batch, bout, out);
}